// Round 2
// baseline (299.516 us; speedup 1.0000x reference)
//
#include <hip/hip_runtime.h>

// GeometryOptimalTransport: B=4, N=M=4096, C=128
// Sinkhorn (3 iters) over log_K(m,n) = -dist2/eps masked to -1e9, then
// attn-weighted gather of source feats.
//
// R2: validity is iteration-invariant -> compact neighbor lists (u16, CAP=512)
// once; run all 6 lse updates + output on the ~3% dense lists. Finite
// NEG_INF=-1e9 contamination is closed-form:
//   - row with 0 valid entries => u = +1e9 EXACTLY (ulp(1e9)=64)
//   - such rows contribute exp(0 - mx) to EVERY column lse => per-batch count cc
//   - all other invalid entries underflow to exactly 0 in fp32.
// R5 post-mortem: cutting partner loads 4x changed NOTHING (119us, identical
// bank-conflict count) -> the sweep's cost is the compaction machinery itself
// (shfl_up scan chain + divergent ctz loop + scattered u16 LDS writes + flush),
// not the loads.
// R6 (this round): ballot-compact. Per 128-partner chunk, the two v_cmp
// results ARE the 64-bit masks (__ballot); each lane's write slot is
// base + popcll(ballot & lanemask_lt) -- pure VALU, no cross-lane scan, no
// divergent extract loop, no LDS at all. Survivors store directly to global
// (consecutive active lanes -> consecutive u16 addresses). List order is
// chunk-major / evens-then-odds, which no consumer cares about (unordered set).

constexpr int   BB = 4;
constexpr int   NN = 4096;
constexpr int   MM = 4096;
constexpr int   CC = 128;
constexpr int   CAP = 512;                          // max neighbors (est max ~330)
constexpr float kNegInf    = -1000000000.0f;
constexpr float kThresh2   = 0.04f;                 // 0.2^2
constexpr float kNegInvEps = -(1.0f / 0.01000001f); // -(1/(EPSILON+1e-8))

__device__ inline float wave_reduce_max(float x) {
#pragma unroll
  for (int off = 32; off > 0; off >>= 1)
    x = fmaxf(x, __shfl_xor(x, off, 64));
  return x;
}
__device__ inline float wave_reduce_sum(float x) {
#pragma unroll
  for (int off = 32; off > 0; off >>= 1)
    x += __shfl_xor(x, off, 64);
  return x;
}

// ---------------------------------------------------------------------------
// FAST PATH (needs ~34 MB workspace)
// ---------------------------------------------------------------------------

// zero v + empty-row counters, fold masks into locs (invalid -> far sentinel;
// DIFFERENT sentinels per side so two invalid points are never "close").
__global__ __launch_bounds__(256) void prep_kernel(
    const float* __restrict__ sloc, const float* __restrict__ tloc,
    const int* __restrict__ sm, const int* __restrict__ tm,
    float* __restrict__ v, int* __restrict__ ecnt,
    float2* __restrict__ slm, float2* __restrict__ tlm)
{
  int i = blockIdx.x * 256 + threadIdx.x;
  if (i < BB * NN) {
    v[i] = 0.0f;
    float2 s = ((const float2*)sloc)[i];
    slm[i] = sm[i] ? s : make_float2(1.0e9f, 1.0e9f);
    float2 t = ((const float2*)tloc)[i];
    tlm[i] = tm[i] ? t : make_float2(3.0e9f, 3.0e9f);
    if (i < BB) ecnt[i] = 0;
  }
}

// Fused row+col neighbor sweep, ballot-compact, one row per wave.
// Blocks [0,4096): row side (a=tlm vs partners=slm);
// blocks [4096,8192): col side (a=slm vs partners=tlm).
// 4 waves/block. Lane L, chunk i tests partners i*128+2L and i*128+2L+1
// (one float4). Write slot = wave-uniform base + popcll(ballot & lanes<L).
__global__ __launch_bounds__(256) void sweep5_kernel(
    const float2* __restrict__ slm, const float2* __restrict__ tlm,
    unsigned short* __restrict__ row_idx, int* __restrict__ row_cnt,
    unsigned short* __restrict__ col_idx, int* __restrict__ col_cnt,
    int* __restrict__ ecnt)
{
  const bool is_row = blockIdx.x < (BB * MM / 4);
  const int  rbase  = (is_row ? blockIdx.x : blockIdx.x - BB * MM / 4) * 4;
  const int  b      = rbase >> 12;
  const int  lane   = threadIdx.x & 63;
  const int  wid    = threadIdx.x >> 6;
  const int  row    = rbase + wid;

  const float2 a = (is_row ? tlm : slm)[row];
  const float4* __restrict__ bl4 =
      (const float4*)((is_row ? slm : tlm) + (size_t)b * 4096);
  unsigned short* __restrict__ lst =
      (is_row ? row_idx : col_idx) + (size_t)row * CAP;

  const unsigned long long lm = (1ull << lane) - 1ull;  // mask of lanes < lane
  int base = 0;

#pragma unroll 8
  for (int i = 0; i < 32; ++i) {
    float4 q = bl4[i * 64 + lane];
    float dx0 = a.x - q.x, dy0 = a.y - q.y;
    float dx1 = a.x - q.z, dy1 = a.y - q.w;
    bool p0 = fmaf(dy0, dy0, dx0 * dx0) < kThresh2;
    bool p1 = fmaf(dy1, dy1, dx1 * dx1) < kThresh2;
    unsigned long long b0 = __ballot(p0);
    unsigned long long b1 = __ballot(p1);
    int c0 = __popcll(b0);
    int pos0 = base + __popcll(b0 & lm);
    int pos1 = base + c0 + __popcll(b1 & lm);
    int nbase = i * 128 + 2 * lane;
    if (p0 && pos0 < CAP) lst[pos0] = (unsigned short)nbase;
    if (p1 && pos1 < CAP) lst[pos1] = (unsigned short)(nbase + 1);
    base += c0 + __popcll(b1);
  }

  if (lane == 0) {
    int cnt = base > CAP ? CAP : base;  // est. max ~330, never hit
    if (is_row) {
      row_cnt[row] = cnt;
      if (cnt == 0) atomicAdd(&ecnt[b], 1);
    } else {
      col_cnt[row] = cnt;
    }
  }
}

// u[row] = cnt ? -lse_j(logK_j + v[n_j]) : +1e9  (one wave per row)
__global__ __launch_bounds__(256) void lse_row_kernel(
    const float2* __restrict__ tlm, const float2* __restrict__ slm,
    const unsigned short* __restrict__ row_idx, const int* __restrict__ row_cnt,
    const float* __restrict__ v, float* __restrict__ u)
{
  const int lane = threadIdx.x & 63;
  const int row  = blockIdx.x * 4 + (threadIdx.x >> 6);
  const int cnt  = row_cnt[row];
  if (cnt == 0) { if (lane == 0) u[row] = 1.0e9f; return; }
  const int b = row >> 12;
  const float2 a = tlm[row];
  const float2* __restrict__ sl = slm + (size_t)b * NN;
  const float*  __restrict__ vb = v + (size_t)b * NN;
  const unsigned short* __restrict__ lst = row_idx + (size_t)row * CAP;

  float t[CAP / 64];
  float mx = -3.0e38f;
#pragma unroll
  for (int i = 0; i < CAP / 64; ++i) {
    int j = i * 64 + lane;
    float tv = -3.0e38f;
    if (j < cnt) {
      int n = lst[j];
      float2 s = sl[n];
      float dx = a.x - s.x, dy = a.y - s.y;
      tv = (dx * dx + dy * dy) * kNegInvEps + vb[n];
    }
    t[i] = tv;
    mx = fmaxf(mx, tv);
  }
  mx = wave_reduce_max(mx);
  float ssum = 0.0f;
#pragma unroll
  for (int i = 0; i < CAP / 64; ++i) ssum += __expf(t[i] - mx);
  ssum = wave_reduce_sum(ssum);
  if (lane == 0) u[row] = -(mx + __logf(ssum));
}

// v[col] = !sv ? 0 : -lse(valid terms + cc copies of t=0)   (one wave per col)
__global__ __launch_bounds__(256) void lse_col_kernel(
    const float2* __restrict__ slm, const float2* __restrict__ tlm,
    const unsigned short* __restrict__ col_idx, const int* __restrict__ col_cnt,
    const int* __restrict__ smask, const int* __restrict__ ecnt,
    const float* __restrict__ u, float* __restrict__ v)
{
  const int lane = threadIdx.x & 63;
  const int col  = blockIdx.x * 4 + (threadIdx.x >> 6);
  if (!smask[col]) { if (lane == 0) v[col] = 0.0f; return; }
  const int cnt = col_cnt[col];
  const int b   = col >> 12;
  const int cc  = ecnt[b];
  if (cnt == 0 && cc == 0) { if (lane == 0) v[col] = 1.0e9f; return; }
  const float2 a = slm[col];
  const float2* __restrict__ tl = tlm + (size_t)b * MM;
  const float*  __restrict__ ub = u + (size_t)b * MM;
  const unsigned short* __restrict__ lst = col_idx + (size_t)col * CAP;

  float t[CAP / 64];
  float mx = -3.0e38f;
#pragma unroll
  for (int i = 0; i < CAP / 64; ++i) {
    int j = i * 64 + lane;
    float tv = -3.0e38f;
    if (j < cnt) {
      int m = lst[j];
      float2 s = tl[m];
      float dx = a.x - s.x, dy = a.y - s.y;
      tv = (dx * dx + dy * dy) * kNegInvEps + ub[m];
    }
    t[i] = tv;
    mx = fmaxf(mx, tv);
  }
  mx = wave_reduce_max(mx);
  if (cc > 0) mx = fmaxf(mx, 0.0f);   // contamination entries are t = 0.0 exactly
  float ssum = 0.0f;
#pragma unroll
  for (int i = 0; i < CAP / 64; ++i) ssum += __expf(t[i] - mx);
  ssum = wave_reduce_sum(ssum);
  if (lane == 0) v[col] = -(mx + __logf(ssum + (float)cc * __expf(0.0f - mx)));
}

// out[row,:] = sum_j attn_j * feats[n_j,:], one block per row, float4 gathers,
// 8 feat rows in flight (group g = tid>>5 handles entries j = g, g+8, ...).
__global__ __launch_bounds__(256) void output2_kernel(
    const float2* __restrict__ tlm, const float2* __restrict__ slm,
    const unsigned short* __restrict__ row_idx, const int* __restrict__ row_cnt,
    const float* __restrict__ u, const float* __restrict__ v,
    const float* __restrict__ feats, float* __restrict__ out)
{
  __shared__ float s_attn[CAP];
  __shared__ unsigned short s_id[CAP];
  __shared__ float4 s_red[256];

  const int row = blockIdx.x;
  const int tid = threadIdx.x;
  const int b   = row >> 12;
  const int cnt = row_cnt[row];
  float4* op = (float4*)(out + (size_t)row * CC);
  if (cnt == 0) {                      // covers !tgt_valid and !has_source
    if (tid < 32) op[tid] = make_float4(0.f, 0.f, 0.f, 0.f);
    return;
  }
  const float um = u[row];
  const float2 a = tlm[row];
  const float2* __restrict__ sl = slm + (size_t)b * NN;
  const float*  __restrict__ vb = v + (size_t)b * NN;
  const unsigned short* __restrict__ lst = row_idx + (size_t)row * CAP;

  for (int j = tid; j < cnt; j += 256) {
    int n = lst[j];
    float2 s = sl[n];
    float dx = a.x - s.x, dy = a.y - s.y;
    s_attn[j] = __expf((dx * dx + dy * dy) * kNegInvEps + um + vb[n]);
    s_id[j] = (unsigned short)n;
  }
  __syncthreads();

  const int g = tid >> 5, l = tid & 31;
  const float4* __restrict__ fb = (const float4*)(feats + (size_t)b * NN * CC);
  float4 acc = make_float4(0.f, 0.f, 0.f, 0.f);
  for (int j = g; j < cnt; j += 8) {
    float aw = s_attn[j];
    int   n  = s_id[j];
    float4 f = fb[(size_t)n * 32 + l];
    acc.x = fmaf(aw, f.x, acc.x);
    acc.y = fmaf(aw, f.y, acc.y);
    acc.z = fmaf(aw, f.z, acc.z);
    acc.w = fmaf(aw, f.w, acc.w);
  }
  s_red[tid] = acc;
  __syncthreads();
  if (tid < 32) {
    float4 r = s_red[tid];
#pragma unroll
    for (int gg = 1; gg < 8; ++gg) {
      float4 p = s_red[gg * 32 + tid];
      r.x += p.x; r.y += p.y; r.z += p.z; r.w += p.w;
    }
    op[tid] = r;
  }
}

// ---------------------------------------------------------------------------
// FALLBACK PATH (round-1 kernels, ~128 KB workspace) — used if ws too small
// ---------------------------------------------------------------------------

__global__ __launch_bounds__(256) void init_v_kernel(float* __restrict__ v) {
  int i = blockIdx.x * 256 + threadIdx.x;
  if (i < BB * NN) v[i] = 0.0f;
}

__global__ __launch_bounds__(256) void u_update_kernel(
    const float* __restrict__ src_locs, const float* __restrict__ tgt_locs,
    const int* __restrict__ src_valid, const int* __restrict__ tgt_valid,
    const float* __restrict__ v, float* __restrict__ u)
{
  const int lane = threadIdx.x & 63;
  const int row  = blockIdx.x * 4 + (threadIdx.x >> 6);
  const int b    = row / MM;
  const float tx = tgt_locs[row * 2 + 0];
  const float ty = tgt_locs[row * 2 + 1];
  const bool  tv = tgt_valid[row] != 0;
  const float2* __restrict__ sl  = (const float2*)(src_locs + (size_t)b * NN * 2);
  const float*  __restrict__ vb  = v + (size_t)b * NN;
  const int*    __restrict__ svb = src_valid + (size_t)b * NN;
  float mx = -3.0e38f;
#pragma unroll 4
  for (int i = 0; i < NN / 64; ++i) {
    int n = i * 64 + lane;
    float2 s = sl[n];
    float dx = tx - s.x, dy = ty - s.y;
    float d2 = dx * dx + dy * dy;
    bool valid = (d2 < kThresh2) & tv & (svb[n] != 0);
    float t = (valid ? d2 * kNegInvEps : kNegInf) + vb[n];
    mx = fmaxf(mx, t);
  }
  mx = wave_reduce_max(mx);
  float s = 0.0f;
#pragma unroll 4
  for (int i = 0; i < NN / 64; ++i) {
    int n = i * 64 + lane;
    float2 sc = sl[n];
    float dx = tx - sc.x, dy = ty - sc.y;
    float d2 = dx * dx + dy * dy;
    bool valid = (d2 < kThresh2) & tv & (svb[n] != 0);
    float t = (valid ? d2 * kNegInvEps : kNegInf) + vb[n];
    s += __expf(t - mx);
  }
  s = wave_reduce_sum(s);
  if (lane == 0) u[row] = -(mx + __logf(s));
}

__global__ __launch_bounds__(256) void v_update_kernel(
    const float* __restrict__ src_locs, const float* __restrict__ tgt_locs,
    const int* __restrict__ src_valid, const int* __restrict__ tgt_valid,
    const float* __restrict__ u, float* __restrict__ v)
{
  const int lane = threadIdx.x & 63;
  const int col  = blockIdx.x * 4 + (threadIdx.x >> 6);
  const int b    = col / NN;
  const float sx = src_locs[col * 2 + 0];
  const float sy = src_locs[col * 2 + 1];
  const bool  sv = src_valid[col] != 0;
  const float2* __restrict__ tl  = (const float2*)(tgt_locs + (size_t)b * MM * 2);
  const float*  __restrict__ ub  = u + (size_t)b * MM;
  const int*    __restrict__ tvb = tgt_valid + (size_t)b * MM;
  float mx = -3.0e38f;
#pragma unroll 4
  for (int i = 0; i < MM / 64; ++i) {
    int m = i * 64 + lane;
    float2 t2 = tl[m];
    float dx = t2.x - sx, dy = t2.y - sy;
    float d2 = dx * dx + dy * dy;
    bool valid = (d2 < kThresh2) & sv & (tvb[m] != 0);
    float t = (valid ? d2 * kNegInvEps : kNegInf) + ub[m];
    mx = fmaxf(mx, t);
  }
  mx = wave_reduce_max(mx);
  float s = 0.0f;
#pragma unroll 4
  for (int i = 0; i < MM / 64; ++i) {
    int m = i * 64 + lane;
    float2 t2 = tl[m];
    float dx = t2.x - sx, dy = t2.y - sy;
    float d2 = dx * dx + dy * dy;
    bool valid = (d2 < kThresh2) & sv & (tvb[m] != 0);
    float t = (valid ? d2 * kNegInvEps : kNegInf) + ub[m];
    s += __expf(t - mx);
  }
  s = wave_reduce_sum(s);
  if (lane == 0) v[col] = sv ? -(mx + __logf(s)) : 0.0f;
}

__global__ __launch_bounds__(256) void output_kernel(
    const float* __restrict__ src_locs, const float* __restrict__ tgt_locs,
    const int* __restrict__ src_valid, const int* __restrict__ tgt_valid,
    const float* __restrict__ u, const float* __restrict__ v,
    const float* __restrict__ feats, float* __restrict__ out)
{
  __shared__ float s_attn[NN];
  __shared__ int   s_idx[NN];
  __shared__ int   s_cnt;
  __shared__ float s_part[CC];
  const int row = blockIdx.x;
  const int b   = row / MM;
  const int tid = threadIdx.x;
  if (tid == 0) s_cnt = 0;
  __syncthreads();
  const float tx = tgt_locs[row * 2 + 0];
  const float ty = tgt_locs[row * 2 + 1];
  const bool  tv = tgt_valid[row] != 0;
  const float um = u[row];
  const float2* __restrict__ sl  = (const float2*)(src_locs + (size_t)b * NN * 2);
  const float*  __restrict__ vb  = v + (size_t)b * NN;
  const int*    __restrict__ svb = src_valid + (size_t)b * NN;
#pragma unroll 4
  for (int i = 0; i < NN / 256; ++i) {
    int n = i * 256 + tid;
    float2 s = sl[n];
    float dx = tx - s.x, dy = ty - s.y;
    float d2 = dx * dx + dy * dy;
    bool valid = (d2 < kThresh2) & tv & (svb[n] != 0);
    if (valid) {
      float a = __expf((d2 * kNegInvEps + um) + vb[n]);
      int p = atomicAdd(&s_cnt, 1);
      s_attn[p] = a;
      s_idx[p]  = n;
    }
  }
  __syncthreads();
  const int cnt = s_cnt;
  const int g = tid >> 7;
  const int c = tid & (CC - 1);
  const float* __restrict__ fb = feats + (size_t)b * NN * CC;
  float acc = 0.0f;
  for (int j = g; j < cnt; j += 2) {
    float a = s_attn[j];
    int   n = s_idx[j];
    acc = fmaf(a, fb[(size_t)n * CC + c], acc);
  }
  if (g == 1) s_part[c] = acc;
  __syncthreads();
  if (g == 0) {
    float r = (cnt > 0) ? (acc + s_part[c]) : 0.0f;
    out[(size_t)row * CC + c] = r;
  }
}

// ---------------------------------------------------------------------------

extern "C" void kernel_launch(void* const* d_in, const int* in_sizes, int n_in,
                              void* d_out, int out_size, void* d_ws, size_t ws_size,
                              hipStream_t stream) {
  const float* feats = (const float*)d_in[0];
  const float* sloc  = (const float*)d_in[1];
  const float* tloc  = (const float*)d_in[2];
  const int*   smask = (const int*)d_in[3];
  const int*   tmask = (const int*)d_in[4];
  float* out = (float*)d_out;

  // workspace layout (fast path)
  char* p = (char*)d_ws;
  float* u_   = (float*)p;            p += (size_t)BB * MM * 4;
  float* v_   = (float*)p;            p += (size_t)BB * NN * 4;
  int* row_cnt = (int*)p;             p += (size_t)BB * MM * 4;
  int* col_cnt = (int*)p;             p += (size_t)BB * NN * 4;
  int* ecnt    = (int*)p;             p += 256;
  float2* slm  = (float2*)p;          p += (size_t)BB * NN * 8;
  float2* tlm  = (float2*)p;          p += (size_t)BB * MM * 8;
  unsigned short* row_idx = (unsigned short*)p; p += (size_t)BB * MM * CAP * 2;
  unsigned short* col_idx = (unsigned short*)p; p += (size_t)BB * NN * CAP * 2;
  size_t required = (size_t)(p - (char*)d_ws);

  if (ws_size >= required) {
    prep_kernel<<<(BB * NN + 255) / 256, 256, 0, stream>>>(
        sloc, tloc, smask, tmask, v_, ecnt, slm, tlm);
    sweep5_kernel<<<2 * BB * MM / 4, 256, 0, stream>>>(
        slm, tlm, row_idx, row_cnt, col_idx, col_cnt, ecnt);
    for (int it = 0; it < 3; ++it) {
      lse_row_kernel<<<BB * MM / 4, 256, 0, stream>>>(tlm, slm, row_idx, row_cnt, v_, u_);
      lse_col_kernel<<<BB * NN / 4, 256, 0, stream>>>(slm, tlm, col_idx, col_cnt,
                                                      smask, ecnt, u_, v_);
    }
    output2_kernel<<<BB * MM, 256, 0, stream>>>(tlm, slm, row_idx, row_cnt,
                                                u_, v_, feats, out);
  } else {
    // fallback: round-1 path (dense re-sweeps), needs only 128 KB
    float* u = (float*)d_ws;
    float* v = u + (size_t)BB * MM;
    init_v_kernel<<<(BB * NN + 255) / 256, 256, 0, stream>>>(v);
    for (int it = 0; it < 3; ++it) {
      u_update_kernel<<<BB * MM / 4, 256, 0, stream>>>(sloc, tloc, smask, tmask, v, u);
      v_update_kernel<<<BB * NN / 4, 256, 0, stream>>>(sloc, tloc, smask, tmask, u, v);
    }
    output_kernel<<<BB * MM, 256, 0, stream>>>(sloc, tloc, smask, tmask, u, v, feats, out);
  }
}

// Round 3
// 245.361 us; speedup vs baseline: 1.2207x; 1.2207x over previous
//
#include <hip/hip_runtime.h>

// GeometryOptimalTransport: B=4, N=M=4096, C=128
// Sinkhorn (3 iters) over log_K(m,n) = -dist2/eps masked to -1e9, then
// attn-weighted gather of source feats.
//
// R2: validity is iteration-invariant -> precompute adjacency once; run all
// 6 lse updates + output on the ~3% dense structure. Finite NEG_INF=-1e9
// contamination is closed-form:
//   - row with 0 valid entries => u = +1e9 EXACTLY (ulp(1e9)=64)
//   - such rows contribute exp(0) to EVERY column lse => per-batch count cc
//   - all other invalid entries underflow to exactly 0 in fp32.
// R5/R6 post-mortems: three sweep variants (LDS-compact, 4-rows/wave,
// ballot-compact) all ~120-135us regardless of load volume or LDS use ->
// the cost is COMPACTION itself (serial position chain + scatter stores).
// R7 (this round): no compaction. Sweep stores each lane's 64-bit predicate
// word directly (permuted bitmap, 512B/row, one coalesced 8B store per lane
// per row). Bit k of lane L's word <=> partner n = (k>>1)*128 + 2L + (k&1).
// Mask built via w = (w>>2) | cndmask -- pure independent VALU, no ballot,
// no scan, no scatter. 4 rows/wave amortizes partner loads. Consumers
// ctz-enumerate their own lane's word (avg 2-5 bits).
// Also: t = d2*(-1/eps) + u/v is bounded (|t| < ~40 << 87) for all entries
// in the bitmap, so lse = log(sum exp(t)) needs NO max pass -> 6 lse kernels
// halve; ssum==0 detects empty rows (cnt arrays deleted; bitmap is exact so
// the CAP=512 truncation hazard is gone).

constexpr int   BB = 4;
constexpr int   NN = 4096;
constexpr int   MM = 4096;
constexpr int   CC = 128;
constexpr float kNegInf    = -1000000000.0f;
constexpr float kThresh2   = 0.04f;                 // 0.2^2
constexpr float kNegInvEps = -(1.0f / 0.01000001f); // -(1/(EPSILON+1e-8))

__device__ inline float wave_reduce_max(float x) {
#pragma unroll
  for (int off = 32; off > 0; off >>= 1)
    x = fmaxf(x, __shfl_xor(x, off, 64));
  return x;
}
__device__ inline float wave_reduce_sum(float x) {
#pragma unroll
  for (int off = 32; off > 0; off >>= 1)
    x += __shfl_xor(x, off, 64);
  return x;
}

// ---------------------------------------------------------------------------
// FAST PATH (needs ~17 MB workspace)
// ---------------------------------------------------------------------------

// zero v + empty-row counters, fold masks into locs (invalid -> far sentinel;
// DIFFERENT sentinels per side so two invalid points are never "close").
__global__ __launch_bounds__(256) void prep_kernel(
    const float* __restrict__ sloc, const float* __restrict__ tloc,
    const int* __restrict__ sm, const int* __restrict__ tm,
    float* __restrict__ v, int* __restrict__ ecnt,
    float2* __restrict__ slm, float2* __restrict__ tlm)
{
  int i = blockIdx.x * 256 + threadIdx.x;
  if (i < BB * NN) {
    v[i] = 0.0f;
    float2 s = ((const float2*)sloc)[i];
    slm[i] = sm[i] ? s : make_float2(1.0e9f, 1.0e9f);
    float2 t = ((const float2*)tloc)[i];
    tlm[i] = tm[i] ? t : make_float2(3.0e9f, 3.0e9f);
    if (i < BB) ecnt[i] = 0;
  }
}

// Fused row+col neighbor sweep -> permuted bitmap. 4 waves/block, 4 rows per
// wave. Blocks [0,1024): row side (a=tlm vs partners=slm); [1024,2048): col
// side. Lane L, iter i tests partners i*128+2L and i*128+2L+1 (one float4);
// bits accumulate via right-shift so no per-iter shift constants are needed:
// after 32 iters, iter i's results sit at bits 2i / 2i+1.
__global__ __launch_bounds__(256) void sweep6_kernel(
    const float2* __restrict__ slm, const float2* __restrict__ tlm,
    unsigned long long* __restrict__ row_bm,
    unsigned long long* __restrict__ col_bm,
    int* __restrict__ ecnt)
{
  constexpr int RPB = 16;                 // rows per block
  const bool is_row = blockIdx.x < (BB * MM / RPB);
  const int  rbase  = (is_row ? blockIdx.x : blockIdx.x - BB * MM / RPB) * RPB;
  const int  b      = rbase >> 12;        // 4096 % 16 == 0: no batch straddle
  const int  lane   = threadIdx.x & 63;
  const int  wid    = threadIdx.x >> 6;
  const int  row0   = rbase + wid * 4;

  const float2* __restrict__ ap = (is_row ? tlm : slm);
  const float2 a0 = ap[row0 + 0];
  const float2 a1 = ap[row0 + 1];
  const float2 a2 = ap[row0 + 2];
  const float2 a3 = ap[row0 + 3];
  const float4* __restrict__ bl4 =
      (const float4*)((is_row ? slm : tlm) + (size_t)b * 4096);

  unsigned long long w0 = 0, w1 = 0, w2 = 0, w3 = 0;
#pragma unroll 8
  for (int i = 0; i < 32; ++i) {
    float4 q = bl4[i * 64 + lane];
#define SWTEST(aa, ww)                                             \
    do {                                                           \
      float dx0 = (aa).x - q.x, dy0 = (aa).y - q.y;                \
      float dx1 = (aa).x - q.z, dy1 = (aa).y - q.w;                \
      bool p0 = fmaf(dy0, dy0, dx0 * dx0) < kThresh2;              \
      bool p1 = fmaf(dy1, dy1, dx1 * dx1) < kThresh2;              \
      ww = (ww >> 2) | (p0 ? (1ull << 62) : 0ull)                  \
                     | (p1 ? (1ull << 63) : 0ull);                 \
    } while (0)
    SWTEST(a0, w0);
    SWTEST(a1, w1);
    SWTEST(a2, w2);
    SWTEST(a3, w3);
#undef SWTEST
  }

  unsigned long long* __restrict__ bm = (is_row ? row_bm : col_bm);
  bm[(size_t)(row0 + 0) * 64 + lane] = w0;
  bm[(size_t)(row0 + 1) * 64 + lane] = w1;
  bm[(size_t)(row0 + 2) * 64 + lane] = w2;
  bm[(size_t)(row0 + 3) * 64 + lane] = w3;

  if (is_row) {
    // empty-row census for the contamination count cc
    unsigned long long z0 = __ballot(w0 != 0ull);
    unsigned long long z1 = __ballot(w1 != 0ull);
    unsigned long long z2 = __ballot(w2 != 0ull);
    unsigned long long z3 = __ballot(w3 != 0ull);
    if (lane == 0) {
      int e = (z0 == 0ull) + (z1 == 0ull) + (z2 == 0ull) + (z3 == 0ull);
      if (e) atomicAdd(&ecnt[b], e);
    }
  }
}

// u[row] = -log(sum_j exp(logK_j + v[n_j])), +1e9 if no valid entries.
// One wave per row; lane L ctz-enumerates its own bitmap word. No max pass:
// all t bounded (|t| << 87), exp cannot over/underflow.
__global__ __launch_bounds__(256) void lse_row_kernel(
    const float2* __restrict__ tlm, const float2* __restrict__ slm,
    const unsigned long long* __restrict__ row_bm,
    const float* __restrict__ v, float* __restrict__ u)
{
  const int lane = threadIdx.x & 63;
  const int row  = blockIdx.x * 4 + (threadIdx.x >> 6);
  const int b    = row >> 12;
  unsigned long long w = row_bm[(size_t)row * 64 + lane];
  const float2 a = tlm[row];
  const float2* __restrict__ sl = slm + (size_t)b * NN;
  const float*  __restrict__ vb = v + (size_t)b * NN;
  float s_l = 0.0f;
  while (w) {
    int k = (int)__builtin_ctzll(w);
    w &= w - 1;
    int n = ((k >> 1) << 7) + 2 * lane + (k & 1);
    float2 s = sl[n];
    float dx = a.x - s.x, dy = a.y - s.y;
    float t = fmaf(dy, dy, dx * dx) * kNegInvEps + vb[n];
    s_l += __expf(t);
  }
  float ssum = wave_reduce_sum(s_l);
  if (lane == 0) u[row] = (ssum == 0.0f) ? 1.0e9f : -__logf(ssum);
}

// v[col] = !sv ? 0 : -log(sum exp(t) + cc); +1e9 if both empty.
__global__ __launch_bounds__(256) void lse_col_kernel(
    const float2* __restrict__ slm, const float2* __restrict__ tlm,
    const unsigned long long* __restrict__ col_bm,
    const int* __restrict__ smask, const int* __restrict__ ecnt,
    const float* __restrict__ u, float* __restrict__ v)
{
  const int lane = threadIdx.x & 63;
  const int col  = blockIdx.x * 4 + (threadIdx.x >> 6);
  if (!smask[col]) { if (lane == 0) v[col] = 0.0f; return; }
  const int b = col >> 12;
  unsigned long long w = col_bm[(size_t)col * 64 + lane];
  const float2 a = slm[col];
  const float2* __restrict__ tl = tlm + (size_t)b * MM;
  const float*  __restrict__ ub = u + (size_t)b * MM;
  float s_l = 0.0f;
  while (w) {
    int k = (int)__builtin_ctzll(w);
    w &= w - 1;
    int m = ((k >> 1) << 7) + 2 * lane + (k & 1);
    float2 s = tl[m];
    float dx = a.x - s.x, dy = a.y - s.y;
    float t = fmaf(dy, dy, dx * dx) * kNegInvEps + ub[m];
    s_l += __expf(t);
  }
  float ssum = wave_reduce_sum(s_l);
  if (lane == 0) {
    float tot = ssum + (float)ecnt[b];   // contamination entries are exp(0)=1
    v[col] = (tot == 0.0f) ? 1.0e9f : -__logf(tot);
  }
}

// out[row,:] = sum_j attn_j * feats[n_j,:], one block per row.
// Phase 1: 256 threads extract the row's bitmap (thread t owns the
// (t&3)-th 16-bit quarter of word t>>2), compute attn, append to LDS via
// atomic slot. Phase 2: 8 groups x 32 lanes gather feats float4.
__global__ __launch_bounds__(256) void output3_kernel(
    const float2* __restrict__ tlm, const float2* __restrict__ slm,
    const unsigned long long* __restrict__ row_bm,
    const float* __restrict__ u, const float* __restrict__ v,
    const float* __restrict__ feats, float* __restrict__ out)
{
  __shared__ float s_attn[1024];
  __shared__ unsigned short s_id[1024];
  __shared__ float4 s_red[256];
  __shared__ int s_cnt;

  const int row = blockIdx.x;
  const int tid = threadIdx.x;
  const int b   = row >> 12;
  if (tid == 0) s_cnt = 0;
  __syncthreads();

  {
    const int L  = tid >> 2;
    const int qp = tid & 3;
    unsigned long long w = row_bm[(size_t)row * 64 + L];
    unsigned wq = (unsigned)(unsigned short)(w >> (qp * 16));
    if (wq) {
      const float um = u[row];
      const float2 a = tlm[row];
      const float2* __restrict__ sl = slm + (size_t)b * NN;
      const float*  __restrict__ vb = v + (size_t)b * NN;
      while (wq) {
        int kk = (int)__builtin_ctz(wq);
        wq &= wq - 1;
        int k = qp * 16 + kk;
        int n = ((k >> 1) << 7) + 2 * L + (k & 1);
        float2 s = sl[n];
        float dx = a.x - s.x, dy = a.y - s.y;
        float aw = __expf(fmaf(dy, dy, dx * dx) * kNegInvEps + um + vb[n]);
        int p = atomicAdd(&s_cnt, 1);
        if (p < 1024) { s_attn[p] = aw; s_id[p] = (unsigned short)n; }
      }
    }
  }
  __syncthreads();

  int cnt = s_cnt;
  if (cnt > 1024) cnt = 1024;             // realistic max ~330, never hit
  float4* op = (float4*)(out + (size_t)row * CC);
  if (cnt == 0) {                         // covers !tgt_valid and !has_source
    if (tid < 32) op[tid] = make_float4(0.f, 0.f, 0.f, 0.f);
    return;
  }

  const int g = tid >> 5, l = tid & 31;
  const float4* __restrict__ fb = (const float4*)(feats + (size_t)b * NN * CC);
  float4 acc = make_float4(0.f, 0.f, 0.f, 0.f);
  for (int j = g; j < cnt; j += 8) {
    float aw = s_attn[j];
    int   n  = s_id[j];
    float4 f = fb[(size_t)n * 32 + l];
    acc.x = fmaf(aw, f.x, acc.x);
    acc.y = fmaf(aw, f.y, acc.y);
    acc.z = fmaf(aw, f.z, acc.z);
    acc.w = fmaf(aw, f.w, acc.w);
  }
  s_red[tid] = acc;
  __syncthreads();
  if (tid < 32) {
    float4 r = s_red[tid];
#pragma unroll
    for (int gg = 1; gg < 8; ++gg) {
      float4 p = s_red[gg * 32 + tid];
      r.x += p.x; r.y += p.y; r.z += p.z; r.w += p.w;
    }
    op[tid] = r;
  }
}

// ---------------------------------------------------------------------------
// FALLBACK PATH (round-1 kernels, ~128 KB workspace) — used if ws too small
// ---------------------------------------------------------------------------

__global__ __launch_bounds__(256) void init_v_kernel(float* __restrict__ v) {
  int i = blockIdx.x * 256 + threadIdx.x;
  if (i < BB * NN) v[i] = 0.0f;
}

__global__ __launch_bounds__(256) void u_update_kernel(
    const float* __restrict__ src_locs, const float* __restrict__ tgt_locs,
    const int* __restrict__ src_valid, const int* __restrict__ tgt_valid,
    const float* __restrict__ v, float* __restrict__ u)
{
  const int lane = threadIdx.x & 63;
  const int row  = blockIdx.x * 4 + (threadIdx.x >> 6);
  const int b    = row / MM;
  const float tx = tgt_locs[row * 2 + 0];
  const float ty = tgt_locs[row * 2 + 1];
  const bool  tv = tgt_valid[row] != 0;
  const float2* __restrict__ sl  = (const float2*)(src_locs + (size_t)b * NN * 2);
  const float*  __restrict__ vb  = v + (size_t)b * NN;
  const int*    __restrict__ svb = src_valid + (size_t)b * NN;
  float mx = -3.0e38f;
#pragma unroll 4
  for (int i = 0; i < NN / 64; ++i) {
    int n = i * 64 + lane;
    float2 s = sl[n];
    float dx = tx - s.x, dy = ty - s.y;
    float d2 = dx * dx + dy * dy;
    bool valid = (d2 < kThresh2) & tv & (svb[n] != 0);
    float t = (valid ? d2 * kNegInvEps : kNegInf) + vb[n];
    mx = fmaxf(mx, t);
  }
  mx = wave_reduce_max(mx);
  float s = 0.0f;
#pragma unroll 4
  for (int i = 0; i < NN / 64; ++i) {
    int n = i * 64 + lane;
    float2 sc = sl[n];
    float dx = tx - sc.x, dy = ty - sc.y;
    float d2 = dx * dx + dy * dy;
    bool valid = (d2 < kThresh2) & tv & (svb[n] != 0);
    float t = (valid ? d2 * kNegInvEps : kNegInf) + vb[n];
    s += __expf(t - mx);
  }
  s = wave_reduce_sum(s);
  if (lane == 0) u[row] = -(mx + __logf(s));
}

__global__ __launch_bounds__(256) void v_update_kernel(
    const float* __restrict__ src_locs, const float* __restrict__ tgt_locs,
    const int* __restrict__ src_valid, const int* __restrict__ tgt_valid,
    const float* __restrict__ u, float* __restrict__ v)
{
  const int lane = threadIdx.x & 63;
  const int col  = blockIdx.x * 4 + (threadIdx.x >> 6);
  const int b    = col / NN;
  const float sx = src_locs[col * 2 + 0];
  const float sy = src_locs[col * 2 + 1];
  const bool  sv = src_valid[col] != 0;
  const float2* __restrict__ tl  = (const float2*)(tgt_locs + (size_t)b * MM * 2);
  const float*  __restrict__ ub  = u + (size_t)b * MM;
  const int*    __restrict__ tvb = tgt_valid + (size_t)b * MM;
  float mx = -3.0e38f;
#pragma unroll 4
  for (int i = 0; i < MM / 64; ++i) {
    int m = i * 64 + lane;
    float2 t2 = tl[m];
    float dx = t2.x - sx, dy = t2.y - sy;
    float d2 = dx * dx + dy * dy;
    bool valid = (d2 < kThresh2) & sv & (tvb[m] != 0);
    float t = (valid ? d2 * kNegInvEps : kNegInf) + ub[m];
    mx = fmaxf(mx, t);
  }
  mx = wave_reduce_max(mx);
  float s = 0.0f;
#pragma unroll 4
  for (int i = 0; i < MM / 64; ++i) {
    int m = i * 64 + lane;
    float2 t2 = tl[m];
    float dx = t2.x - sx, dy = t2.y - sy;
    float d2 = dx * dx + dy * dy;
    bool valid = (d2 < kThresh2) & sv & (tvb[m] != 0);
    float t = (valid ? d2 * kNegInvEps : kNegInf) + ub[m];
    s += __expf(t - mx);
  }
  s = wave_reduce_sum(s);
  if (lane == 0) v[col] = sv ? -(mx + __logf(s)) : 0.0f;
}

__global__ __launch_bounds__(256) void output_kernel(
    const float* __restrict__ src_locs, const float* __restrict__ tgt_locs,
    const int* __restrict__ src_valid, const int* __restrict__ tgt_valid,
    const float* __restrict__ u, const float* __restrict__ v,
    const float* __restrict__ feats, float* __restrict__ out)
{
  __shared__ float s_attn[NN];
  __shared__ int   s_idx[NN];
  __shared__ int   s_cnt;
  __shared__ float s_part[CC];
  const int row = blockIdx.x;
  const int b   = row / MM;
  const int tid = threadIdx.x;
  if (tid == 0) s_cnt = 0;
  __syncthreads();
  const float tx = tgt_locs[row * 2 + 0];
  const float ty = tgt_locs[row * 2 + 1];
  const bool  tv = tgt_valid[row] != 0;
  const float um = u[row];
  const float2* __restrict__ sl  = (const float2*)(src_locs + (size_t)b * NN * 2);
  const float*  __restrict__ vb  = v + (size_t)b * NN;
  const int*    __restrict__ svb = src_valid + (size_t)b * NN;
#pragma unroll 4
  for (int i = 0; i < NN / 256; ++i) {
    int n = i * 256 + tid;
    float2 s = sl[n];
    float dx = tx - s.x, dy = ty - s.y;
    float d2 = dx * dx + dy * dy;
    bool valid = (d2 < kThresh2) & tv & (svb[n] != 0);
    if (valid) {
      float a = __expf((d2 * kNegInvEps + um) + vb[n]);
      int p = atomicAdd(&s_cnt, 1);
      s_attn[p] = a;
      s_idx[p]  = n;
    }
  }
  __syncthreads();
  const int cnt = s_cnt;
  const int g = tid >> 7;
  const int c = tid & (CC - 1);
  const float* __restrict__ fb = feats + (size_t)b * NN * CC;
  float acc = 0.0f;
  for (int j = g; j < cnt; j += 2) {
    float a = s_attn[j];
    int   n = s_idx[j];
    acc = fmaf(a, fb[(size_t)n * CC + c], acc);
  }
  if (g == 1) s_part[c] = acc;
  __syncthreads();
  if (g == 0) {
    float r = (cnt > 0) ? (acc + s_part[c]) : 0.0f;
    out[(size_t)row * CC + c] = r;
  }
}

// ---------------------------------------------------------------------------

extern "C" void kernel_launch(void* const* d_in, const int* in_sizes, int n_in,
                              void* d_out, int out_size, void* d_ws, size_t ws_size,
                              hipStream_t stream) {
  const float* feats = (const float*)d_in[0];
  const float* sloc  = (const float*)d_in[1];
  const float* tloc  = (const float*)d_in[2];
  const int*   smask = (const int*)d_in[3];
  const int*   tmask = (const int*)d_in[4];
  float* out = (float*)d_out;

  // workspace layout (fast path): ~17 MB
  char* p = (char*)d_ws;
  float* u_   = (float*)p;            p += (size_t)BB * MM * 4;
  float* v_   = (float*)p;            p += (size_t)BB * NN * 4;
  int* ecnt   = (int*)p;              p += 256;
  float2* slm = (float2*)p;           p += (size_t)BB * NN * 8;
  float2* tlm = (float2*)p;           p += (size_t)BB * MM * 8;
  unsigned long long* row_bm = (unsigned long long*)p; p += (size_t)BB * MM * 64 * 8;
  unsigned long long* col_bm = (unsigned long long*)p; p += (size_t)BB * NN * 64 * 8;
  size_t required = (size_t)(p - (char*)d_ws);

  if (ws_size >= required) {
    prep_kernel<<<(BB * NN + 255) / 256, 256, 0, stream>>>(
        sloc, tloc, smask, tmask, v_, ecnt, slm, tlm);
    sweep6_kernel<<<2 * BB * MM / 16, 256, 0, stream>>>(
        slm, tlm, row_bm, col_bm, ecnt);
    for (int it = 0; it < 3; ++it) {
      lse_row_kernel<<<BB * MM / 4, 256, 0, stream>>>(tlm, slm, row_bm, v_, u_);
      lse_col_kernel<<<BB * NN / 4, 256, 0, stream>>>(slm, tlm, col_bm,
                                                      smask, ecnt, u_, v_);
    }
    output3_kernel<<<BB * MM, 256, 0, stream>>>(tlm, slm, row_bm,
                                                u_, v_, feats, out);
  } else {
    // fallback: round-1 path (dense re-sweeps), needs only 128 KB
    float* u = (float*)d_ws;
    float* v = u + (size_t)BB * MM;
    init_v_kernel<<<(BB * NN + 255) / 256, 256, 0, stream>>>(v);
    for (int it = 0; it < 3; ++it) {
      u_update_kernel<<<BB * MM / 4, 256, 0, stream>>>(sloc, tloc, smask, tmask, v, u);
      v_update_kernel<<<BB * NN / 4, 256, 0, stream>>>(sloc, tloc, smask, tmask, u, v);
    }
    output_kernel<<<BB * MM, 256, 0, stream>>>(sloc, tloc, smask, tmask, u, v, feats, out);
  }
}